// Round 5
// baseline (450.639 us; speedup 1.0000x reference)
//
#include <hip/hip_runtime.h>

#define D_DIM 128
#define HALF_D 64      // packed-bf16x2 elements per row
#define RPB 64         // rows per bucket
#define RPB_SHIFT 6
#define MAXNB 2048     // LDS histogram bound (NB = 1563 here)
#define NBLK 128       // hist/scatter grid: open-tail-line footprint = NBLK*NB*64B ~ 16.8 MB < L2
#define CHUNK 2560     // max edges per bucket handled by LDS sort (mean 2048, sigma 45)
#define KSTAGE 10      // CHUNK / 256 threads

// ---------------- phase 0: h -> packed bf16 (RNE), float4-vectorized; zero bucket counts
__global__ void convert_h4(const float4* __restrict__ h4, uint2* __restrict__ hb2, int n4,
                           int* __restrict__ counts, int NB) {
    int i = blockIdx.x * blockDim.x + threadIdx.x;
    if (i < NB) counts[i] = 0;          // fold memset into this pass (runs before hist)
    if (i < n4) {
        float4 p = h4[i];
        unsigned b0 = __float_as_uint(p.x);
        unsigned b1 = __float_as_uint(p.y);
        unsigned b2 = __float_as_uint(p.z);
        unsigned b3 = __float_as_uint(p.w);
        unsigned r0 = (b0 + 0x7FFFu + ((b0 >> 16) & 1u)) >> 16;
        unsigned r1 = (b1 + 0x7FFFu + ((b1 >> 16) & 1u)) & 0xFFFF0000u;
        unsigned r2 = (b2 + 0x7FFFu + ((b2 >> 16) & 1u)) >> 16;
        unsigned r3 = (b3 + 0x7FFFu + ((b3 >> 16) & 1u)) & 0xFFFF0000u;
        hb2[i] = make_uint2(r0 | r1, r2 | r3);
    }
}

// ---------------- phase 1: bucket histogram; STASH per-block hist for reuse ----------
__global__ __launch_bounds__(1024) void bucket_hist(const int* __restrict__ row,
                                                    int* __restrict__ counts,
                                                    int* __restrict__ histS,
                                                    int E, int NB) {
    __shared__ int h[MAXNB];
    for (int i = threadIdx.x; i < NB; i += blockDim.x) h[i] = 0;
    __syncthreads();
    int chunk = (E + gridDim.x - 1) / gridDim.x;
    int lo = blockIdx.x * chunk;
    int hi = min(E, lo + chunk);
    for (int e = lo + threadIdx.x; e < hi; e += blockDim.x)
        atomicAdd(&h[row[e] >> RPB_SHIFT], 1);
    __syncthreads();
    for (int i = threadIdx.x; i < NB; i += blockDim.x) {
        int c = h[i];
        histS[(size_t)blockIdx.x * NB + i] = c;   // stash: scatter reuses, no re-hist
        if (c) atomicAdd(&counts[i], c);
    }
}

// ---------------- phase 2: scan bucket counts (one block) ----------------
__global__ __launch_bounds__(256) void bucket_scan(const int* __restrict__ counts,
                                                   int* __restrict__ off, int NB) {
    __shared__ int tot[256];
    int t = threadIdx.x;
    int vals[8];
    int s = 0;
    for (int k = 0; k < 8; ++k) {
        int i = t * 8 + k;
        int c = (i < NB) ? counts[i] : 0;
        s += c;
        vals[k] = s;                 // inclusive within thread
    }
    tot[t] = s;
    __syncthreads();
    for (int d = 1; d < 256; d <<= 1) {   // Hillis-Steele inclusive
        int v = (t >= d) ? tot[t - d] : 0;
        __syncthreads();
        tot[t] += v;
        __syncthreads();
    }
    int base = (t > 0) ? tot[t - 1] : 0;
    for (int k = 0; k < 8; ++k) {
        int i = t * 8 + k;
        if (i < NB) off[i + 1] = base + vals[k];
    }
    if (t == 0) off[0] = 0;
}

// ---------------- phase 2b: per-(block,bucket) write bases -> zero atomics in scatter --
__global__ void block_bases(const int* __restrict__ off, const int* __restrict__ histS,
                            int* __restrict__ bb, int NB, int nblk) {
    int b = blockIdx.x * blockDim.x + threadIdx.x;
    if (b >= NB) return;
    int run = off[b];
    for (int k = 0; k < nblk; ++k) {
        bb[(size_t)k * NB + b] = run;
        run += histS[(size_t)k * NB + b];
    }
}

// ---------------- phase 3: scatter, precomputed bases, no hist pass, no global atomics --
__global__ __launch_bounds__(1024) void bucket_scatter(const int* __restrict__ row,
        const int* __restrict__ col, const float* __restrict__ val,
        const int* __restrict__ bb, int2* __restrict__ sorted, int E, int NB) {
    __shared__ int cur[MAXNB];
    for (int i = threadIdx.x; i < NB; i += blockDim.x)
        cur[i] = bb[(size_t)blockIdx.x * NB + i];
    __syncthreads();
    int chunk = (E + gridDim.x - 1) / gridDim.x;
    int lo = blockIdx.x * chunk;
    int hi = min(E, lo + chunk);
    for (int e = lo + threadIdx.x; e < hi; e += blockDim.x) {
        int r = row[e];
        int b = r >> RPB_SHIFT;
        int p = atomicAdd(&cur[b], 1);
        // pack: low 20 bits = col (N < 2^20), bits 20..25 = local row
        sorted[p] = make_int2(col[e] | ((r & (RPB - 1)) << 20), __float_as_int(val[e]));
    }
}

// ---------------- phase 4: FUSED within-bucket row sort (LDS) + aggregation ----------
__global__ __launch_bounds__(256) void sort_aggregate(
        const int* __restrict__ off, const int2* __restrict__ ed,
        const uint4* __restrict__ hb4, const float4* __restrict__ h04,
        float4* __restrict__ out4, int N) {
    __shared__ int2 buf[CHUNK];
    __shared__ int cnt[RPB];
    __shared__ int segs[RPB];
    __shared__ int cur[RPB];
    int b = blockIdx.x;
    int tid = threadIdx.x;
    int t = tid & 63;
    int w = tid >> 6;
    int g = t >> 4;        // edge group 0..3
    int l = t & 15;        // dim-chunk lane: dims 8l..8l+7
    int start = off[b], end = off[b + 1];
    int nE = end - start;
    int row0 = b << RPB_SHIFT;

    if (nE <= CHUNK) {
        if (tid < RPB) cnt[tid] = 0;
        __syncthreads();
        int ex[KSTAGE], ey[KSTAGE];
        #pragma unroll
        for (int k = 0; k < KSTAGE; ++k) {
            int idx = start + tid + k * 256;
            if (idx < end) {
                int2 e = ed[idx];
                ex[k] = e.x; ey[k] = e.y;
                atomicAdd(&cnt[(e.x >> 20) & (RPB - 1)], 1);
            } else {
                ex[k] = -1;
            }
        }
        __syncthreads();
        if (tid < RPB) {
            int v = cnt[tid];
            int inc = v;
            #pragma unroll
            for (int d = 1; d < RPB; d <<= 1) {
                int x = __shfl_up(inc, d);
                if (tid >= d) inc += x;
            }
            segs[tid] = inc - v;   // segment start (0-based in buf)
            cur[tid]  = inc - v;   // scatter cursor
        }
        __syncthreads();
        #pragma unroll
        for (int k = 0; k < KSTAGE; ++k) {
            if (ex[k] != -1) {
                int p = atomicAdd(&cur[(ex[k] >> 20) & (RPB - 1)], 1);
                buf[p] = make_int2(ex[k] & 0xFFFFF, ey[k]);
            }
        }
        __syncthreads();           // after this, cur[lr] == segment end
        for (int lr = w; lr < RPB; lr += 4) {
            int r = row0 + lr;
            if (r >= N) break;
            int s0 = segs[lr], s1 = cur[lr];
            float a0 = 0.f, a1 = 0.f, a2 = 0.f, a3 = 0.f;
            float a4 = 0.f, a5 = 0.f, a6 = 0.f, a7 = 0.f;
            #pragma unroll 4
            for (int base = s0; base < s1; base += 4) {
                int ei = base + g;
                int2 e = (ei < s1) ? buf[ei] : make_int2(0, 0);  // v=0 kills pad lanes
                float v = __int_as_float(e.y);
                uint4 q = hb4[((size_t)(unsigned)e.x << 4) + l];
                a0 = fmaf(v, __uint_as_float(q.x << 16), a0);
                a1 = fmaf(v, __uint_as_float(q.x & 0xFFFF0000u), a1);
                a2 = fmaf(v, __uint_as_float(q.y << 16), a2);
                a3 = fmaf(v, __uint_as_float(q.y & 0xFFFF0000u), a3);
                a4 = fmaf(v, __uint_as_float(q.z << 16), a4);
                a5 = fmaf(v, __uint_as_float(q.z & 0xFFFF0000u), a5);
                a6 = fmaf(v, __uint_as_float(q.w << 16), a6);
                a7 = fmaf(v, __uint_as_float(q.w & 0xFFFF0000u), a7);
            }
            a0 += __shfl_xor(a0, 16); a0 += __shfl_xor(a0, 32);
            a1 += __shfl_xor(a1, 16); a1 += __shfl_xor(a1, 32);
            a2 += __shfl_xor(a2, 16); a2 += __shfl_xor(a2, 32);
            a3 += __shfl_xor(a3, 16); a3 += __shfl_xor(a3, 32);
            a4 += __shfl_xor(a4, 16); a4 += __shfl_xor(a4, 32);
            a5 += __shfl_xor(a5, 16); a5 += __shfl_xor(a5, 32);
            a6 += __shfl_xor(a6, 16); a6 += __shfl_xor(a6, 32);
            a7 += __shfl_xor(a7, 16); a7 += __shfl_xor(a7, 32);
            if (t < 16) {
                size_t o = (size_t)r * 32 + 2 * l;
                float4 g0 = h04[o];
                float4 g1 = h04[o + 1];
                out4[o]     = make_float4(fmaf(0.9f, a0, 0.1f * g0.x),
                                          fmaf(0.9f, a1, 0.1f * g0.y),
                                          fmaf(0.9f, a2, 0.1f * g0.z),
                                          fmaf(0.9f, a3, 0.1f * g0.w));
                out4[o + 1] = make_float4(fmaf(0.9f, a4, 0.1f * g1.x),
                                          fmaf(0.9f, a5, 0.1f * g1.y),
                                          fmaf(0.9f, a6, 0.1f * g1.z),
                                          fmaf(0.9f, a7, 0.1f * g1.w));
            }
        }
    } else {
        for (int lr = w; lr < RPB; lr += 4) {
            int r = row0 + lr;
            if (r >= N) break;
            float a0 = 0.f, a1 = 0.f, a2 = 0.f, a3 = 0.f;
            float a4 = 0.f, a5 = 0.f, a6 = 0.f, a7 = 0.f;
            for (int base = start; base < end; base += 4) {
                int ei = base + g;
                int2 e = (ei < end) ? ed[ei] : make_int2(0, 0);
                float v = (((e.x >> 20) & (RPB - 1)) == lr) ? __int_as_float(e.y) : 0.f;
                uint4 q = hb4[((size_t)(unsigned)(e.x & 0xFFFFF) << 4) + l];
                a0 = fmaf(v, __uint_as_float(q.x << 16), a0);
                a1 = fmaf(v, __uint_as_float(q.x & 0xFFFF0000u), a1);
                a2 = fmaf(v, __uint_as_float(q.y << 16), a2);
                a3 = fmaf(v, __uint_as_float(q.y & 0xFFFF0000u), a3);
                a4 = fmaf(v, __uint_as_float(q.z << 16), a4);
                a5 = fmaf(v, __uint_as_float(q.z & 0xFFFF0000u), a5);
                a6 = fmaf(v, __uint_as_float(q.w << 16), a6);
                a7 = fmaf(v, __uint_as_float(q.w & 0xFFFF0000u), a7);
            }
            a0 += __shfl_xor(a0, 16); a0 += __shfl_xor(a0, 32);
            a1 += __shfl_xor(a1, 16); a1 += __shfl_xor(a1, 32);
            a2 += __shfl_xor(a2, 16); a2 += __shfl_xor(a2, 32);
            a3 += __shfl_xor(a3, 16); a3 += __shfl_xor(a3, 32);
            a4 += __shfl_xor(a4, 16); a4 += __shfl_xor(a4, 32);
            a5 += __shfl_xor(a5, 16); a5 += __shfl_xor(a5, 32);
            a6 += __shfl_xor(a6, 16); a6 += __shfl_xor(a6, 32);
            a7 += __shfl_xor(a7, 16); a7 += __shfl_xor(a7, 32);
            if (t < 16) {
                size_t o = (size_t)r * 32 + 2 * l;
                float4 g0 = h04[o];
                float4 g1 = h04[o + 1];
                out4[o]     = make_float4(fmaf(0.9f, a0, 0.1f * g0.x),
                                          fmaf(0.9f, a1, 0.1f * g0.y),
                                          fmaf(0.9f, a2, 0.1f * g0.z),
                                          fmaf(0.9f, a3, 0.1f * g0.w));
                out4[o + 1] = make_float4(fmaf(0.9f, a4, 0.1f * g1.x),
                                          fmaf(0.9f, a5, 0.1f * g1.y),
                                          fmaf(0.9f, a6, 0.1f * g1.z),
                                          fmaf(0.9f, a7, 0.1f * g1.w));
            }
        }
    }
}

// ---------------- fallback: direct atomic scatter ----------------
__global__ void init_out(const float* __restrict__ h0, float* __restrict__ out, int n) {
    int i = blockIdx.x * blockDim.x + threadIdx.x;
    if (i < n) out[i] = 0.1f * h0[i];
}

__global__ void scatter_atomic(const int* __restrict__ row, const int* __restrict__ col,
                               const float* __restrict__ val, const float* __restrict__ h,
                               float* __restrict__ out, int E) {
    long idx = (long)blockIdx.x * blockDim.x + threadIdx.x;
    int e = (int)(idx >> 6);
    if (e >= E) return;
    int t = (int)(idx & 63);
    int r = row[e], c = col[e];
    float v = 0.9f * val[e];
    atomicAdd(&out[(size_t)r * D_DIM + 2 * t],     v * h[(size_t)c * D_DIM + 2 * t]);
    atomicAdd(&out[(size_t)r * D_DIM + 2 * t + 1], v * h[(size_t)c * D_DIM + 2 * t + 1]);
}

extern "C" void kernel_launch(void* const* d_in, const int* in_sizes, int n_in,
                              void* d_out, int out_size, void* d_ws, size_t ws_size,
                              hipStream_t stream) {
    const int*   edge_row = (const int*)d_in[0];
    const int*   edge_col = (const int*)d_in[1];
    const float* edge_val = (const float*)d_in[2];
    const float* h        = (const float*)d_in[3];
    const float* h0       = (const float*)d_in[4];
    float*       out      = (float*)d_out;

    const int E  = in_sizes[0];
    const int N  = in_sizes[3] / D_DIM;
    const int NB = (N + RPB - 1) / RPB;

    auto align16 = [](size_t x) { return (x + 15) & ~(size_t)15; };
    size_t counts_off  = 0;
    size_t off_off     = align16(counts_off + (size_t)NB * 4);
    size_t hists_off   = align16(off_off + (size_t)(NB + 1) * 4);
    size_t bb_off      = align16(hists_off + (size_t)NBLK * NB * 4);
    size_t sorted_off  = align16(bb_off + (size_t)NBLK * NB * 4);
    size_t hbf_off     = align16(sorted_off + (size_t)E * 8);
    size_t ws_need     = hbf_off + (size_t)N * HALF_D * 4;   // + bf16 h copy

    char* ws = (char*)d_ws;
    bool ok = (ws_size >= ws_need) && (NB <= MAXNB) && (N < (1 << 20));
    if (ok) {
        int*  counts  = (int*)(ws + counts_off);
        int*  offs    = (int*)(ws + off_off);
        int*  histS   = (int*)(ws + hists_off);
        int*  bb      = (int*)(ws + bb_off);
        int2* sorted  = (int2*)(ws + sorted_off);
        unsigned int* hbf = (unsigned int*)(ws + hbf_off);

        int n4 = N * (D_DIM / 4);          // float4 elements in h
        convert_h4<<<(n4 + 255) / 256, 256, 0, stream>>>((const float4*)h,
                                                         (uint2*)hbf, n4, counts, NB);
        bucket_hist<<<NBLK, 1024, 0, stream>>>(edge_row, counts, histS, E, NB);
        bucket_scan<<<1, 256, 0, stream>>>(counts, offs, NB);
        block_bases<<<(NB + 255) / 256, 256, 0, stream>>>(offs, histS, bb, NB, NBLK);
        bucket_scatter<<<NBLK, 1024, 0, stream>>>(edge_row, edge_col, edge_val,
                                                  bb, sorted, E, NB);
        sort_aggregate<<<NB, 256, 0, stream>>>(offs, sorted, (const uint4*)hbf,
                                               (const float4*)h0, (float4*)out, N);
    } else {
        int nd = N * D_DIM;
        init_out<<<(nd + 255) / 256, 256, 0, stream>>>(h0, out, nd);
        long total_threads = (long)E * 64;
        scatter_atomic<<<(int)((total_threads + 255) / 256), 256, 0, stream>>>(
            edge_row, edge_col, edge_val, h, out, E);
    }
}

// Round 7
// 330.590 us; speedup vs baseline: 1.3631x; 1.3631x over previous
//
#include <hip/hip_runtime.h>

#define D_DIM 128
#define HALF_D 64      // packed-bf16x2 elements per row
#define RPB 64         // rows per bucket
#define RPB_SHIFT 6
#define MAXNB 2048     // bucket-count bound (NB = 1563 here)
#define NSEG 512       // tile_sort grid = segments per bucket
#define CHUNK_A 6272   // max edges per tile_sort block (LDS buf 50 KB)
#define CHUNK 2560     // max edges per bucket in sort_aggregate (mean 2048, sigma 45)
#define KSTAGE 10      // CHUNK / 256 threads

// ---------------- phase 0: h -> packed bf16 (RNE), float4-vectorized ----------------
// hb[i] = bf16(h[2i]) low 16 | bf16(h[2i+1]) high 16
__global__ void convert_h4(const float4* __restrict__ h4, uint2* __restrict__ hb2, int n4) {
    int i = blockIdx.x * blockDim.x + threadIdx.x;
    if (i < n4) {
        float4 p = h4[i];
        unsigned b0 = __float_as_uint(p.x);
        unsigned b1 = __float_as_uint(p.y);
        unsigned b2 = __float_as_uint(p.z);
        unsigned b3 = __float_as_uint(p.w);
        unsigned r0 = (b0 + 0x7FFFu + ((b0 >> 16) & 1u)) >> 16;
        unsigned r1 = (b1 + 0x7FFFu + ((b1 >> 16) & 1u)) & 0xFFFF0000u;
        unsigned r2 = (b2 + 0x7FFFu + ((b2 >> 16) & 1u)) >> 16;
        unsigned r3 = (b3 + 0x7FFFu + ((b3 >> 16) & 1u)) & 0xFFFF0000u;
        hb2[i] = make_uint2(r0 | r1, r2 | r3);
    }
}

// ---------------- phase 1: block-major tile sort ----------------
// Block k counting-sorts its contiguous edge chunk [k*chunk, k*chunk+n) by bucket
// ENTIRELY IN LDS, then streams it back contiguously (write amp = 1.0 by
// construction) and records segment starts S[b][k] = k*chunk + excl_k[b].
// S is b-major so sort_aggregate's reads of S[b][*] are coalesced.
__global__ __launch_bounds__(1024) void tile_sort(const int* __restrict__ row,
        const int* __restrict__ col, const float* __restrict__ val,
        int* __restrict__ S, int2* __restrict__ sorted, int E, int NB, int chunk) {
    __shared__ int2 buf[CHUNK_A];   // 50176 B
    __shared__ int  cur[MAXNB];     // 8192 B: hist -> cursors
    __shared__ int  tot[1024];      // 4096 B: block scan
    int k = blockIdx.x, t = threadIdx.x;
    int lo = k * chunk;
    int hi = min(E, lo + chunk);
    int n  = (hi > lo) ? (hi - lo) : 0;
    cur[t] = 0; cur[t + 1024] = 0;
    __syncthreads();
    for (int e = lo + t; e < hi; e += 1024)
        atomicAdd(&cur[row[e] >> RPB_SHIFT], 1);
    __syncthreads();
    // exclusive scan over 2048 bins: thread owns bins (2t, 2t+1)
    int b0 = 2 * t, b1 = 2 * t + 1;
    int c0 = cur[b0], c1 = cur[b1];
    tot[t] = c0 + c1;
    __syncthreads();
    for (int d = 1; d < 1024; d <<= 1) {
        int v = (t >= d) ? tot[t - d] : 0;
        __syncthreads();
        tot[t] += v;
        __syncthreads();
    }
    int base = (t > 0) ? tot[t - 1] : 0;
    if (b0 < NB) S[(size_t)b0 * NSEG + k] = lo + base;
    if (b1 < NB) S[(size_t)b1 * NSEG + k] = lo + base + c0;
    if (t == 0)  S[(size_t)NB * NSEG + k] = lo + n;
    cur[b0] = base;            // local scatter cursors
    cur[b1] = base + c0;
    __syncthreads();
    for (int e = lo + t; e < hi; e += 1024) {
        int r = row[e];
        int b = r >> RPB_SHIFT;
        int p = atomicAdd(&cur[b], 1);
        // pack: low 20 bits = col (N < 2^20), bits 20..25 = local row
        buf[p] = make_int2(col[e] | ((r & (RPB - 1)) << 20), __float_as_int(val[e]));
    }
    __syncthreads();
    for (int i = t; i < n; i += 1024)
        sorted[lo + i] = buf[i];   // contiguous streaming write, full lines
}

// ---------------- phase 2: segmented stage + LDS row sort + aggregation ----------
// Bucket b's edges live in 512 segments [S[b][k], S[b+1][k]). Stage them via an
// LDS prefix + binary search (consecutive lanes -> consecutive slots -> reads stay
// segment-locally coalesced), then identical LDS row-sort + gather as before.
__global__ __launch_bounds__(256) void sort_aggregate(
        const int* __restrict__ S, const int2* __restrict__ ed,
        const uint4* __restrict__ hb4, const float4* __restrict__ h04,
        float4* __restrict__ out4, int N) {
    __shared__ int2 buf[CHUNK];      // 20480 B
    __shared__ int slo[NSEG];        // 2048 B: segment start indices
    __shared__ int P[NSEG + 1];      // 2052 B: exclusive prefix of segment lengths
    __shared__ int tot[256];         // 1024 B
    __shared__ int cnt[RPB];
    __shared__ int segs[RPB];
    __shared__ int cur[RPB];
    int b = blockIdx.x;
    int tid = threadIdx.x;
    int t = tid & 63;
    int w = tid >> 6;
    int g = t >> 4;        // edge group 0..3
    int l = t & 15;        // dim-chunk lane: dims 8l..8l+7
    int row0 = b << RPB_SHIFT;

    // segment bounds + prefix scan (thread owns segments 2tid, 2tid+1)
    int k0 = 2 * tid, k1 = k0 + 1;
    int a0 = S[(size_t)b * NSEG + k0];
    int a1 = S[(size_t)b * NSEG + k1];
    int e0 = S[(size_t)(b + 1) * NSEG + k0];
    int e1 = S[(size_t)(b + 1) * NSEG + k1];
    int l0 = e0 - a0, l1 = e1 - a1;
    slo[k0] = a0; slo[k1] = a1;
    tot[tid] = l0 + l1;
    __syncthreads();
    for (int d = 1; d < 256; d <<= 1) {
        int v = (tid >= d) ? tot[tid - d] : 0;
        __syncthreads();
        tot[tid] += v;
        __syncthreads();
    }
    int base = (tid > 0) ? tot[tid - 1] : 0;
    P[k0] = base; P[k1] = base + l0;
    if (tid == 255) P[NSEG] = tot[255];
    __syncthreads();
    int nE = P[NSEG];

    // binary search: largest s with P[s] <= i
    auto seg_of = [&](int i) {
        int s_ = 0;
        #pragma unroll
        for (int w_ = 256; w_; w_ >>= 1)
            if (P[s_ + w_] <= i) s_ += w_;
        return s_;
    };

    if (nE <= CHUNK) {
        if (tid < RPB) cnt[tid] = 0;
        __syncthreads();
        int ex[KSTAGE], ey[KSTAGE];
        #pragma unroll
        for (int k = 0; k < KSTAGE; ++k) {
            int i = tid + k * 256;
            if (i < nE) {
                int s_ = seg_of(i);
                int2 e = ed[slo[s_] + (i - P[s_])];
                ex[k] = e.x; ey[k] = e.y;
                atomicAdd(&cnt[(e.x >> 20) & (RPB - 1)], 1);
            } else {
                ex[k] = -1;   // packed e.x is always >= 0 (26 bits)
            }
        }
        __syncthreads();
        if (tid < RPB) {
            int v = cnt[tid];
            int inc = v;
            #pragma unroll
            for (int d = 1; d < RPB; d <<= 1) {
                int x = __shfl_up(inc, d);
                if (tid >= d) inc += x;
            }
            segs[tid] = inc - v;   // segment start (0-based in buf)
            cur[tid]  = inc - v;   // scatter cursor
        }
        __syncthreads();
        #pragma unroll
        for (int k = 0; k < KSTAGE; ++k) {
            if (ex[k] != -1) {
                int p = atomicAdd(&cur[(ex[k] >> 20) & (RPB - 1)], 1);
                buf[p] = make_int2(ex[k] & 0xFFFFF, ey[k]);
            }
        }
        __syncthreads();           // after this, cur[lr] == segment end
        for (int lr = w; lr < RPB; lr += 4) {
            int r = row0 + lr;
            if (r >= N) break;
            int s0 = segs[lr], s1 = cur[lr];
            float a0f = 0.f, a1f = 0.f, a2f = 0.f, a3f = 0.f;
            float a4f = 0.f, a5f = 0.f, a6f = 0.f, a7f = 0.f;
            #pragma unroll 4
            for (int bb = s0; bb < s1; bb += 4) {
                int ei = bb + g;
                int2 e = (ei < s1) ? buf[ei] : make_int2(0, 0);  // v=0 kills pad lanes
                float v = __int_as_float(e.y);
                uint4 q = hb4[((size_t)(unsigned)e.x << 4) + l];
                a0f = fmaf(v, __uint_as_float(q.x << 16), a0f);
                a1f = fmaf(v, __uint_as_float(q.x & 0xFFFF0000u), a1f);
                a2f = fmaf(v, __uint_as_float(q.y << 16), a2f);
                a3f = fmaf(v, __uint_as_float(q.y & 0xFFFF0000u), a3f);
                a4f = fmaf(v, __uint_as_float(q.z << 16), a4f);
                a5f = fmaf(v, __uint_as_float(q.z & 0xFFFF0000u), a5f);
                a6f = fmaf(v, __uint_as_float(q.w << 16), a6f);
                a7f = fmaf(v, __uint_as_float(q.w & 0xFFFF0000u), a7f);
            }
            a0f += __shfl_xor(a0f, 16); a0f += __shfl_xor(a0f, 32);
            a1f += __shfl_xor(a1f, 16); a1f += __shfl_xor(a1f, 32);
            a2f += __shfl_xor(a2f, 16); a2f += __shfl_xor(a2f, 32);
            a3f += __shfl_xor(a3f, 16); a3f += __shfl_xor(a3f, 32);
            a4f += __shfl_xor(a4f, 16); a4f += __shfl_xor(a4f, 32);
            a5f += __shfl_xor(a5f, 16); a5f += __shfl_xor(a5f, 32);
            a6f += __shfl_xor(a6f, 16); a6f += __shfl_xor(a6f, 32);
            a7f += __shfl_xor(a7f, 16); a7f += __shfl_xor(a7f, 32);
            if (t < 16) {
                size_t o = (size_t)r * 32 + 2 * l;
                float4 g0 = h04[o];
                float4 g1 = h04[o + 1];
                out4[o]     = make_float4(fmaf(0.9f, a0f, 0.1f * g0.x),
                                          fmaf(0.9f, a1f, 0.1f * g0.y),
                                          fmaf(0.9f, a2f, 0.1f * g0.z),
                                          fmaf(0.9f, a3f, 0.1f * g0.w));
                out4[o + 1] = make_float4(fmaf(0.9f, a4f, 0.1f * g1.x),
                                          fmaf(0.9f, a5f, 0.1f * g1.y),
                                          fmaf(0.9f, a6f, 0.1f * g1.z),
                                          fmaf(0.9f, a7f, 0.1f * g1.w));
            }
        }
    } else {
        // ---- fallback (statistically never: needs a bucket > 2560 edges, +11 sigma) ----
        // correct-but-slow: init rows then fp32 atomics from segments
        const unsigned* hb = (const unsigned*)hb4;
        const float* h0f = (const float*)h04;
        float* outf = (float*)out4;
        for (int i = tid; i < RPB * D_DIM; i += 256) {
            int r = row0 + i / D_DIM;
            if (r < N) outf[(size_t)r * D_DIM + (i % D_DIM)] =
                           0.1f * h0f[(size_t)r * D_DIM + (i % D_DIM)];
        }
        __syncthreads();
        for (int i = tid; i < nE; i += 256) {
            int s_ = seg_of(i);
            int2 e = ed[slo[s_] + (i - P[s_])];
            int lr = (e.x >> 20) & (RPB - 1);
            int c  = e.x & 0xFFFFF;
            float v = 0.9f * __int_as_float(e.y);
            int r = row0 + lr;
            if (r < N) {
                for (int d = 0; d < HALF_D; ++d) {
                    unsigned u = hb[(size_t)c * HALF_D + d];
                    atomicAdd(&outf[(size_t)r * D_DIM + 2 * d],
                              v * __uint_as_float(u << 16));
                    atomicAdd(&outf[(size_t)r * D_DIM + 2 * d + 1],
                              v * __uint_as_float(u & 0xFFFF0000u));
                }
            }
        }
    }
}

// ---------------- fallback: direct atomic scatter ----------------
__global__ void init_out(const float* __restrict__ h0, float* __restrict__ out, int n) {
    int i = blockIdx.x * blockDim.x + threadIdx.x;
    if (i < n) out[i] = 0.1f * h0[i];
}

__global__ void scatter_atomic(const int* __restrict__ row, const int* __restrict__ col,
                               const float* __restrict__ val, const float* __restrict__ h,
                               float* __restrict__ out, int E) {
    long idx = (long)blockIdx.x * blockDim.x + threadIdx.x;
    int e = (int)(idx >> 6);
    if (e >= E) return;
    int t = (int)(idx & 63);
    int r = row[e], c = col[e];
    float v = 0.9f * val[e];
    atomicAdd(&out[(size_t)r * D_DIM + 2 * t],     v * h[(size_t)c * D_DIM + 2 * t]);
    atomicAdd(&out[(size_t)r * D_DIM + 2 * t + 1], v * h[(size_t)c * D_DIM + 2 * t + 1]);
}

extern "C" void kernel_launch(void* const* d_in, const int* in_sizes, int n_in,
                              void* d_out, int out_size, void* d_ws, size_t ws_size,
                              hipStream_t stream) {
    const int*   edge_row = (const int*)d_in[0];
    const int*   edge_col = (const int*)d_in[1];
    const float* edge_val = (const float*)d_in[2];
    const float* h        = (const float*)d_in[3];
    const float* h0       = (const float*)d_in[4];
    float*       out      = (float*)d_out;

    const int E  = in_sizes[0];
    const int N  = in_sizes[3] / D_DIM;
    const int NB = (N + RPB - 1) / RPB;
    const int chunk = (E + NSEG - 1) / NSEG;   // 6250 here

    auto align16 = [](size_t x) { return (x + 15) & ~(size_t)15; };
    size_t S_off      = 0;
    size_t sorted_off = align16(S_off + (size_t)(NB + 1) * NSEG * 4);
    size_t hbf_off    = align16(sorted_off + (size_t)E * 8);
    size_t ws_need    = hbf_off + (size_t)N * HALF_D * 4;

    char* ws = (char*)d_ws;
    bool ok = (ws_size >= ws_need) && (NB <= MAXNB) && (N < (1 << 20)) &&
              (chunk <= CHUNK_A) && (E > 0);
    if (ok) {
        int*  S      = (int*)(ws + S_off);
        int2* sorted = (int2*)(ws + sorted_off);
        unsigned int* hbf = (unsigned int*)(ws + hbf_off);

        int n4 = N * (D_DIM / 4);          // float4 elements in h
        convert_h4<<<(n4 + 255) / 256, 256, 0, stream>>>((const float4*)h,
                                                         (uint2*)hbf, n4);
        tile_sort<<<NSEG, 1024, 0, stream>>>(edge_row, edge_col, edge_val,
                                             S, sorted, E, NB, chunk);
        sort_aggregate<<<NB, 256, 0, stream>>>(S, sorted, (const uint4*)hbf,
                                               (const float4*)h0, (float4*)out, N);
    } else {
        int nd = N * D_DIM;
        init_out<<<(nd + 255) / 256, 256, 0, stream>>>(h0, out, nd);
        long total_threads = (long)E * 64;
        scatter_atomic<<<(int)((total_threads + 255) / 256), 256, 0, stream>>>(
            edge_row, edge_col, edge_val, h, out, E);
    }
}